// Round 1
// baseline (73.383 us; speedup 1.0000x reference)
//
#include <hip/hip_runtime.h>
#include <math.h>

#define EPS 1e-6f
#define CAP 1024
#define BB 64
#define LL 1024
#define CC 512
#define DD 5
#define LCH 16
#define LPC (LL / LCH) /* 64 l's per chunk */

// ---------- kernel 1: partial sums over l-chunks -----------------------------
// grid = BB*LCH blocks, 128 threads; thread t owns 4 consecutive c (float4)
__global__ void k_partial(const float* __restrict__ x,
                          float* __restrict__ psum, float* __restrict__ psq) {
    const int blk = blockIdx.x;            // b*LCH + ch
    const int b = blk / LCH, ch = blk % LCH;
    const int c = threadIdx.x * 4;
    const float4* xp = (const float4*)(x + ((size_t)b * LL + (size_t)ch * LPC) * CC + c);
    float4 s = make_float4(0.f, 0.f, 0.f, 0.f);
    float4 q = make_float4(0.f, 0.f, 0.f, 0.f);
#pragma unroll 8
    for (int l = 0; l < LPC; ++l) {
        float4 v = xp[(size_t)l * (CC / 4)];
        s.x += v.x; s.y += v.y; s.z += v.z; s.w += v.w;
        q.x += v.x * v.x; q.y += v.y * v.y; q.z += v.z * v.z; q.w += v.w * v.w;
    }
    float* ps = psum + (size_t)blk * CC + c;
    float* pq = psq + (size_t)blk * CC + c;
    *(float4*)ps = s;
    *(float4*)pq = q;
}

// ---------- kernel 2: finalize mean / sig ------------------------------------
// 8192 threads total: each owns (b, c4) -> float4 of C
__global__ void k_stats(const float* __restrict__ psum, const float* __restrict__ psq,
                        float* __restrict__ mu, float* __restrict__ sig) {
    const int t = blockIdx.x * blockDim.x + threadIdx.x;   // 0..8191
    const int b = t / (CC / 4), c4 = t % (CC / 4);
    float4 s = make_float4(0.f, 0.f, 0.f, 0.f);
    float4 q = make_float4(0.f, 0.f, 0.f, 0.f);
    for (int ch = 0; ch < LCH; ++ch) {
        const float4 vs = ((const float4*)(psum + (size_t)(b * LCH + ch) * CC))[c4];
        const float4 vq = ((const float4*)(psq + (size_t)(b * LCH + ch) * CC))[c4];
        s.x += vs.x; s.y += vs.y; s.z += vs.z; s.w += vs.w;
        q.x += vq.x; q.y += vq.y; q.z += vq.z; q.w += vq.w;
    }
    const float inv_n = 1.0f / (float)LL;
    const float inv_n1 = 1.0f / (float)(LL - 1);
    float4 m, g;
    m.x = s.x * inv_n; m.y = s.y * inv_n; m.z = s.z * inv_n; m.w = s.w * inv_n;
    g.x = sqrtf(fmaxf((q.x - (float)LL * m.x * m.x) * inv_n1, 0.f) + EPS);
    g.y = sqrtf(fmaxf((q.y - (float)LL * m.y * m.y) * inv_n1, 0.f) + EPS);
    g.z = sqrtf(fmaxf((q.z - (float)LL * m.z * m.z) * inv_n1, 0.f) + EPS);
    g.w = sqrtf(fmaxf((q.w - (float)LL * m.w * m.w) * inv_n1, 0.f) + EPS);
    ((float4*)(mu + (size_t)b * CC))[c4] = m;
    ((float4*)(sig + (size_t)b * CC))[c4] = g;
}

// ---------- kernel 3: ranks, positions, gather-source index ------------------
// 1 block, 64 threads
__global__ void k_index(const int* __restrict__ domain, const int* __restrict__ d1,
                        const int* __restrict__ f1, const int* __restrict__ offsets,
                        int* __restrict__ src) {
    __shared__ int dom_s[BB];
    __shared__ int pos_s[BB];
    const int b = threadIdx.x;
    dom_s[b] = domain[b];
    __syncthreads();
    const int db = dom_s[b];
    int rank = 0;
    for (int j = 0; j < b; ++j) rank += (dom_s[j] == db) ? 1 : 0;
    pos_s[b] = (offsets[db] + rank) & (CAP - 1);
    __syncthreads();
    const int dd = d1[b], ff = f1[b];
    int s = -1;
    for (int j = 0; j < BB; ++j)
        if (dom_s[j] == dd && pos_s[j] == ff) s = j;
    src[b] = s;
}

// ---------- kernel 4: per-(b,c) affine coefficients --------------------------
// 8192 threads
__global__ void k_coeff(const float* __restrict__ mu, const float* __restrict__ sig,
                        const float* __restrict__ mq, const float* __restrict__ sq,
                        const float* __restrict__ lmda, const int* __restrict__ d1,
                        const int* __restrict__ f1, const int* __restrict__ src,
                        float* __restrict__ scale, float* __restrict__ shift) {
    const int t = blockIdx.x * blockDim.x + threadIdx.x;   // 0..8191
    const int b = t / (CC / 4), c4 = t % (CC / 4);
    const int c = c4 * 4;
    const float lm = lmda[b];
    const float om = 1.0f - lm;
    const int s = src[b];
    const float4 m = *(const float4*)(mu + (size_t)b * CC + c);
    const float4 g = *(const float4*)(sig + (size_t)b * CC + c);
    float4 m1, g1;
    if (s >= 0) {
        m1 = *(const float4*)(mu + (size_t)s * CC + c);
        g1 = *(const float4*)(sig + (size_t)s * CC + c);
    } else {
        const size_t base = ((size_t)d1[b] * CAP + (size_t)f1[b]) * CC + c;
        m1 = *(const float4*)(mq + base);
        g1 = *(const float4*)(sq + base);
    }
    float4 sc, sh;
    {
        float mm = m.x * lm + m1.x * om, gm = g.x * lm + g1.x * om;
        sc.x = gm / g.x; sh.x = mm - m.x * sc.x;
        mm = m.y * lm + m1.y * om; gm = g.y * lm + g1.y * om;
        sc.y = gm / g.y; sh.y = mm - m.y * sc.y;
        mm = m.z * lm + m1.z * om; gm = g.z * lm + g1.z * om;
        sc.z = gm / g.z; sh.z = mm - m.z * sc.z;
        mm = m.w * lm + m1.w * om; gm = g.w * lm + g1.w * om;
        sc.w = gm / g.w; sh.w = mm - m.w * sc.w;
    }
    *(float4*)(scale + (size_t)b * CC + c) = sc;
    *(float4*)(shift + (size_t)b * CC + c) = sh;
}

// ---------- kernel 5: out = x*scale + shift ----------------------------------
// 8388608 threads (float4 each)
__global__ void k_out(const float* __restrict__ x, const float* __restrict__ scale,
                      const float* __restrict__ shift, float* __restrict__ out) {
    const size_t t = (size_t)blockIdx.x * blockDim.x + threadIdx.x; // over [B][L][C/4]
    const int b = (int)(t >> 17);        // t / (L*C/4) = t / 131072
    const int c4 = (int)(t & 127);       // t % (C/4)
    const float4 v = ((const float4*)x)[t];
    const float4 sc = ((const float4*)scale)[b * (CC / 4) + c4];
    const float4 sh = ((const float4*)shift)[b * (CC / 4) + c4];
    float4 o;
    o.x = fmaf(v.x, sc.x, sh.x);
    o.y = fmaf(v.y, sc.y, sh.y);
    o.z = fmaf(v.z, sc.z, sh.z);
    o.w = fmaf(v.w, sc.w, sh.w);
    ((float4*)out)[t] = o;
}

extern "C" void kernel_launch(void* const* d_in, const int* in_sizes, int n_in,
                              void* d_out, int out_size, void* d_ws, size_t ws_size,
                              hipStream_t stream) {
    const float* x       = (const float*)d_in[0];
    const int*   domain  = (const int*)d_in[1];
    const float* mq      = (const float*)d_in[2];
    const float* sq      = (const float*)d_in[3];
    const float* lmda    = (const float*)d_in[4];
    const int*   d1      = (const int*)d_in[5];
    const int*   f1      = (const int*)d_in[6];
    const int*   offsets = (const int*)d_in[7];
    float* out = (float*)d_out;

    // workspace layout (float offsets, all 16B-aligned)
    float* ws      = (float*)d_ws;
    float* f_mu    = ws;                    // 32768
    float* f_sig   = ws + 32768;            // 32768
    float* f_scale = ws + 65536;            // 32768
    float* f_shift = ws + 98304;            // 32768
    int*   i_src   = (int*)(ws + 131072);   // 64 ints
    float* f_psum  = ws + 131072 + 64;      // 524288
    float* f_psq   = f_psum + 524288;       // 524288

    hipLaunchKernelGGL(k_partial, dim3(BB * LCH), dim3(128), 0, stream,
                       x, f_psum, f_psq);
    hipLaunchKernelGGL(k_stats, dim3(32), dim3(256), 0, stream,
                       f_psum, f_psq, f_mu, f_sig);
    hipLaunchKernelGGL(k_index, dim3(1), dim3(BB), 0, stream,
                       domain, d1, f1, offsets, i_src);
    hipLaunchKernelGGL(k_coeff, dim3(32), dim3(256), 0, stream,
                       f_mu, f_sig, mq, sq, lmda, d1, f1, i_src, f_scale, f_shift);
    hipLaunchKernelGGL(k_out, dim3((BB * LL * CC / 4) / 256), dim3(256), 0, stream,
                       x, f_scale, f_shift, out);
}

// Round 3
// 68.987 us; speedup vs baseline: 1.0637x; 1.0637x over previous
//
#include <hip/hip_runtime.h>
#include <math.h>

#define EPS 1e-6f
#define CAP 1024
#define BB 64
#define LL 1024
#define CC 512
#define LCH 16
#define LPC (LL / LCH) /* 64 rows per chunk */

typedef float f32x4 __attribute__((ext_vector_type(4)));

// ---------- kernel 1: partial sums over l-chunks -----------------------------
// grid = BB*LCH blocks, 128 threads; thread t owns 4 consecutive c (float4)
__global__ __launch_bounds__(128) void k_partial(const float* __restrict__ x,
                          float* __restrict__ psum, float* __restrict__ psq) {
    const int blk = blockIdx.x;            // b*LCH + ch
    const int b = blk / LCH, ch = blk % LCH;
    const int c = threadIdx.x * 4;
    const f32x4* xp = (const f32x4*)(x + ((size_t)b * LL + (size_t)ch * LPC) * CC + c);
    f32x4 s = (f32x4)0.f;
    f32x4 q = (f32x4)0.f;
#pragma unroll 8
    for (int l = 0; l < LPC; ++l) {
        f32x4 v = xp[(size_t)l * (CC / 4)];
        s += v;
        q += v * v;
    }
    *(f32x4*)(psum + (size_t)blk * CC + c) = s;
    *(f32x4*)(psq  + (size_t)blk * CC + c) = q;
}

// ---------- helper: reduce per-sample stats from partials --------------------
__device__ inline void reduce_stats(const float* __restrict__ psum,
                                    const float* __restrict__ psq,
                                    int b, int c4, f32x4& m, f32x4& g) {
    f32x4 s = (f32x4)0.f;
    f32x4 q = (f32x4)0.f;
#pragma unroll
    for (int ch = 0; ch < LCH; ++ch) {
        s += ((const f32x4*)(psum + (size_t)(b * LCH + ch) * CC))[c4];
        q += ((const f32x4*)(psq  + (size_t)(b * LCH + ch) * CC))[c4];
    }
    const float inv_n  = 1.0f / (float)LL;
    const float inv_n1 = 1.0f / (float)(LL - 1);
    m = s * inv_n;
#pragma unroll
    for (int j = 0; j < 4; ++j) {
        float var = (q[j] - (float)LL * m[j] * m[j]) * inv_n1;
        g[j] = sqrtf(fmaxf(var, 0.f) + EPS);
    }
}

// ---------- kernel 2 (fused): stats finalize + index + coefficients ----------
// 32 blocks x 256 threads; thread t owns (b = t/128, c4 = t%128)
__global__ __launch_bounds__(256) void k_mid(const float* __restrict__ psum, const float* __restrict__ psq,
                      const float* __restrict__ mq, const float* __restrict__ sq,
                      const float* __restrict__ lmda, const int* __restrict__ domain,
                      const int* __restrict__ d1, const int* __restrict__ f1,
                      const int* __restrict__ offsets,
                      float* __restrict__ scale, float* __restrict__ shift) {
    __shared__ int dom_s[BB];
    __shared__ int pos_s[BB];
    __shared__ int src_s[2];
    const int tid = threadIdx.x;
    const int t = blockIdx.x * 256 + tid;   // 0..8191
    const int b = t >> 7, c4 = t & 127;

    if (tid < BB) dom_s[tid] = domain[tid];
    __syncthreads();
    if (tid < BB) {
        const int d = dom_s[tid];
        int rank = 0;
        for (int j = 0; j < tid; ++j) rank += (dom_s[j] == d) ? 1 : 0;
        pos_s[tid] = (offsets[d] + rank) & (CAP - 1);
    }
    __syncthreads();
    if (tid < 2) {
        const int bb = blockIdx.x * 2 + tid;
        const int dd = d1[bb], ff = f1[bb];
        int s = -1;
        for (int j = 0; j < BB; ++j)
            if (dom_s[j] == dd && pos_s[j] == ff) s = j;
        src_s[tid] = s;
    }
    __syncthreads();

    f32x4 m, g;
    reduce_stats(psum, psq, b, c4, m, g);

    const int s = src_s[b & 1];
    f32x4 m1, g1;
    if (s >= 0) {
        reduce_stats(psum, psq, s, c4, m1, g1);
    } else {
        const size_t base = ((size_t)d1[b] * CAP + (size_t)f1[b]) * CC + c4 * 4;
        m1 = *(const f32x4*)(mq + base);
        g1 = *(const f32x4*)(sq + base);
    }

    const float lm = lmda[b];
    const float om = 1.0f - lm;
    f32x4 sc, sh;
#pragma unroll
    for (int j = 0; j < 4; ++j) {
        const float mm = m[j] * lm + m1[j] * om;
        const float gm = g[j] * lm + g1[j] * om;
        sc[j] = gm / g[j];
        sh[j] = mm - m[j] * sc[j];
    }
    ((f32x4*)(scale + (size_t)b * CC))[c4] = sc;
    ((f32x4*)(shift + (size_t)b * CC))[c4] = sh;
}

// ---------- kernel 3: out = x*scale + shift (2 float4 / thread, NT stores) ---
__global__ __launch_bounds__(256) void k_out(const float* __restrict__ x, const float* __restrict__ scale,
                      const float* __restrict__ shift, float* __restrict__ out) {
    const size_t base = (size_t)blockIdx.x * 512 + threadIdx.x; // elem idx in float4 units
#pragma unroll
    for (int r = 0; r < 2; ++r) {
        const size_t e = base + (size_t)r * 256;   // < 8388608
        const int b  = (int)(e >> 17);             // / (L*C/4)
        const int c4 = (int)(e & 127);             // % (C/4)
        const f32x4 v  = ((const f32x4*)x)[e];
        const f32x4 sc = ((const f32x4*)scale)[b * (CC / 4) + c4];
        const f32x4 sh = ((const f32x4*)shift)[b * (CC / 4) + c4];
        f32x4 o;
#pragma unroll
        for (int j = 0; j < 4; ++j) o[j] = fmaf(v[j], sc[j], sh[j]);
        __builtin_nontemporal_store(o, (f32x4*)out + e);
    }
}

extern "C" void kernel_launch(void* const* d_in, const int* in_sizes, int n_in,
                              void* d_out, int out_size, void* d_ws, size_t ws_size,
                              hipStream_t stream) {
    const float* x       = (const float*)d_in[0];
    const int*   domain  = (const int*)d_in[1];
    const float* mq      = (const float*)d_in[2];
    const float* sq      = (const float*)d_in[3];
    const float* lmda    = (const float*)d_in[4];
    const int*   d1      = (const int*)d_in[5];
    const int*   f1      = (const int*)d_in[6];
    const int*   offsets = (const int*)d_in[7];
    float* out = (float*)d_out;

    // workspace layout (float offsets, all 16B-aligned)
    float* ws      = (float*)d_ws;
    float* f_scale = ws;                    // 32768
    float* f_shift = ws + 32768;            // 32768
    float* f_psum  = ws + 65536;            // 524288
    float* f_psq   = f_psum + 524288;       // 524288

    hipLaunchKernelGGL(k_partial, dim3(BB * LCH), dim3(128), 0, stream,
                       x, f_psum, f_psq);
    hipLaunchKernelGGL(k_mid, dim3(32), dim3(256), 0, stream,
                       f_psum, f_psq, mq, sq, lmda, domain, d1, f1, offsets,
                       f_scale, f_shift);
    hipLaunchKernelGGL(k_out, dim3((BB * LL * CC / 4) / 512), dim3(256), 0, stream,
                       x, f_scale, f_shift, out);
}